// Round 6
// baseline (329.071 us; speedup 1.0000x reference)
//
#include <hip/hip_runtime.h>
#include <stdint.h>

// out[m,n] = -sqrt( ||A[m]||^2 + ||B[n]||^2 - 2*A[m].B[n] )
// A = features [M=16384, K=2048], B = prototypes [N=1000, K=2048].
//
// Stage plan (ws >= 71.3 MB):
//  1. prep_kernel: fp32 -> bf16(rne) of A,B into workspace + exact fp32 row
//     norms. (bf16 input: plain copy + norms.)
//  2. gemm_kernel: 256x256 tile, BK=64, 512 threads (8 waves, 2Mx4N), 128 KiB
//     double-buffered LDS, 16x16x32 bf16 MFMA. NEW: 4-phase interleaved
//     schedule (m194-m201 template port): per K-tile, 4 quadrant-clusters of
//     16 MFMA, each phase = {ds_read next cluster's frags || stage slice ->
//     barrier -> lgkmcnt(0) -> setprio MFMA setprio -> barrier}; vmcnt(0)
//     once per tile at ph3 (stages issued >=2 phases earlier -> no drain
//     stall). Linear LDS dest + inverse-swizzled global source (chunk ^=
//     row&7), swizzled ds_read (0 conflicts measured). Grid 256 blocks =
//     1/CU; XCD-chunked swizzle.
//  3. ws too small -> round-2 verified fused kernel (correctness fallback).

#define KDIM 2048

typedef __attribute__((ext_vector_type(8))) __bf16 bf16x8;
typedef __attribute__((ext_vector_type(4))) float f32x4;

#define BAR() do { asm volatile("" ::: "memory"); __builtin_amdgcn_s_barrier(); asm volatile("" ::: "memory"); } while (0)

__device__ __forceinline__ bool sniff_is_f32(const void* Araw) {
  // bf16 N(0,1) data -> max |x| < 10; fp32 data -> mantissa half-words give
  // |x| > 1e4 essentially surely. Uniform across all blocks/lanes.
  const uint16_t* sniff = (const uint16_t*)Araw;
  float mx = 0.f;
#pragma unroll
  for (int i = 0; i < 64; ++i) {
    float v = __uint_as_float(((uint32_t)sniff[i]) << 16);
    mx = fmaxf(mx, fabsf(v));
  }
  return mx > 1e4f;
}

__device__ __forceinline__ uint32_t bf16rn(uint32_t u) {
  // fp32 bits -> bf16 bits, round-to-nearest-even (finite inputs only)
  return (u + 0x7FFFu + ((u >> 16) & 1u)) >> 16;
}
__device__ __forceinline__ uint32_t pack_rn(uint32_t a, uint32_t b) {
  return bf16rn(a) | (bf16rn(b) << 16);
}

__device__ __forceinline__ void gload_lds16(const void* g, void* l) {
  // async 16B global -> LDS; dest = wave-uniform base + lane*16
  __builtin_amdgcn_global_load_lds(
      (const __attribute__((address_space(1))) void*)g,
      (__attribute__((address_space(3))) void*)l, 16, 0, 0);
}

// ----------------------------------------------------- prepass: cvt+norms ----
// one wave per row; 4 rows per 256-thread block
__global__ __launch_bounds__(256) void prep_kernel(
    const void* __restrict__ Araw, const void* __restrict__ Braw,
    uint16_t* __restrict__ Abf, uint16_t* __restrict__ Bbf,
    float* __restrict__ fsq, float* __restrict__ psq, int M, int N) {
  const bool isf32 = sniff_is_f32(Araw);
  const int wave = threadIdx.x >> 6;
  const int lane = threadIdx.x & 63;
  const int row = blockIdx.x * 4 + wave;
  if (row >= M + N) return;
  const bool isA = row < M;
  const size_t r = isA ? (size_t)row : (size_t)(row - M);
  uint2* dst = (uint2*)((isA ? Abf : Bbf) + r * KDIM);
  float s = 0.f;
  if (isf32) {
    const float* p = (isA ? (const float*)Araw : (const float*)Braw) + r * KDIM;
#pragma unroll
    for (int it = 0; it < KDIM / 256; ++it) {
      float4 v = *((const float4*)p + it * 64 + lane);
      s = fmaf(v.x, v.x, fmaf(v.y, v.y, fmaf(v.z, v.z, fmaf(v.w, v.w, s))));
      uint2 o;
      o.x = pack_rn(__float_as_uint(v.x), __float_as_uint(v.y));
      o.y = pack_rn(__float_as_uint(v.z), __float_as_uint(v.w));
      dst[it * 64 + lane] = o;
    }
  } else {
    const uint16_t* p =
        (isA ? (const uint16_t*)Araw : (const uint16_t*)Braw) + r * KDIM;
#pragma unroll
    for (int it = 0; it < KDIM / 256; ++it) {
      uint2 v = *((const uint2*)p + it * 64 + lane);
      float e0 = __uint_as_float(v.x << 16);
      float e1 = __uint_as_float(v.x & 0xFFFF0000u);
      float e2 = __uint_as_float(v.y << 16);
      float e3 = __uint_as_float(v.y & 0xFFFF0000u);
      s = fmaf(e0, e0, fmaf(e1, e1, fmaf(e2, e2, fmaf(e3, e3, s))));
      dst[it * 64 + lane] = v;
    }
  }
#pragma unroll
  for (int o = 32; o > 0; o >>= 1) s += __shfl_down(s, o, 64);
  if (lane == 0) {
    if (isA) fsq[r] = s;
    else     psq[r] = s;
  }
}

// --------------------------------------------------- GEMM 256x256, BK=64 ----
#define BM2 256
#define BN2 256
#define BK2 64
#define NK2 (KDIM / BK2)   // 32

__global__ __launch_bounds__(512, 2) void gemm_kernel(
    const uint16_t* __restrict__ Abf, const uint16_t* __restrict__ Bbf,
    const float* __restrict__ fsq, const float* __restrict__ psq,
    float* __restrict__ out, int M, int N) {
  // row = 64 bf16 = 128 B = 8 chunks of 16 B. LDS chunk c of row r holds
  // global k-chunk c ^ (r&7)  (inverse-swizzled SOURCE, linear dest).
  __shared__ uint32_t Ab[2][BM2][32];  // 64 KB
  __shared__ uint32_t Bb[2][BN2][32];  // 64 KB

  const int tid = threadIdx.x;
  const int lane = tid & 63;
  const int wave = tid >> 6;   // 0..7

  // XCD-chunked block swizzle (nwg = 256, divisible by 8 -> bijective).
  const int gx = gridDim.x, gy = gridDim.y;
  const int nwg = gx * gy;
  int id = blockIdx.y * gx + blockIdx.x;
  if ((nwg & 7) == 0) id = (id & 7) * (nwg >> 3) + (id >> 3);
  const int m0 = (id / gx) * BM2;
  const int n0 = (id % gx) * BN2;

  const int wr = wave >> 2;   // 0..1: 128-row band
  const int wc = wave & 3;    // 0..3: 64-col band
  const int lr = lane & 15;   // fragment row/col within 16
  const int lg = lane >> 4;   // k-group within 4

  const int wbase = (tid & ~63);  // wave*64, uniform in wave

  // stage one half-tile (128 rows) of matrix mat into buffer b for K-tile ks
  auto stage_half = [&](int b, int ks, int mat, int h) {
#pragma unroll
    for (int l = 0; l < 2; ++l) {
      const int f = l * 512 + tid;          // 16B-chunk id within half
      const int row = h * 128 + (f >> 3);
      const int gc = (f & 7) ^ (row & 7);   // pre-swizzled source chunk
      uint32_t* base = mat ? &Bb[b][0][0] : &Ab[b][0][0];
      uint32_t* dst = base + h * 4096 + (l * 512 + wbase) * 4;  // wave-uniform
      const int lim = mat ? N : M;
      int g = (mat ? n0 : m0) + row;
      g = g < lim ? g : lim - 1;            // clamp tail rows
      const uint16_t* G = mat ? Bbf : Abf;
      gload_lds16(G + (size_t)g * KDIM + ks * BK2 + gc * 8, dst);
    }
  };

  bf16x8 A0[4][2], A1[4][2], B0[2][2], B1[2][2];

  auto readA = [&](bf16x8 (&dst)[4][2], int b, int mh) {
#pragma unroll
    for (int i = 0; i < 4; ++i) {
      const int r = wr * 128 + (mh * 4 + i) * 16 + lr;
#pragma unroll
      for (int kk = 0; kk < 2; ++kk) {
        const int pc = (((kk << 2) + lg) ^ (r & 7)) * 4;
        dst[i][kk] = *(const bf16x8*)&Ab[b][r][pc];
      }
    }
  };
  auto readB = [&](bf16x8 (&dst)[2][2], int b, int nh) {
#pragma unroll
    for (int j = 0; j < 2; ++j) {
      const int r = wc * 64 + (nh * 2 + j) * 16 + lr;
#pragma unroll
      for (int kk = 0; kk < 2; ++kk) {
        const int pc = (((kk << 2) + lg) ^ (r & 7)) * 4;
        dst[j][kk] = *(const bf16x8*)&Bb[b][r][pc];
      }
    }
  };

  f32x4 acc[8][4] = {};

  auto cluster = [&](bf16x8 (&A)[4][2], bf16x8 (&B)[2][2], int mh, int nh) {
    __builtin_amdgcn_s_setprio(1);
#pragma unroll
    for (int i = 0; i < 4; ++i)
#pragma unroll
      for (int j = 0; j < 2; ++j)
#pragma unroll
        for (int kk = 0; kk < 2; ++kk)
          acc[mh * 4 + i][nh * 2 + j] = __builtin_amdgcn_mfma_f32_16x16x32_bf16(
              A[i][kk], B[j][kk], acc[mh * 4 + i][nh * 2 + j], 0, 0, 0);
    __builtin_amdgcn_s_setprio(0);
  };

  // prologue: stage K-tile 0 fully, drain, visibility barrier
  stage_half(0, 0, 0, 0); stage_half(0, 0, 0, 1);
  stage_half(0, 0, 1, 0); stage_half(0, 0, 1, 1);
  asm volatile("s_waitcnt vmcnt(0)" ::: "memory");
  BAR();

  for (int ks = 0; ks < NK2; ++ks) {
    const int buf = ks & 1, nbuf = buf ^ 1;
    const bool pf = (ks + 1 < NK2);

    // ---- ph0: cluster (0,0); reads RA0+RB0; stage A-halves of ks+1 ----
    readA(A0, buf, 0);
    readB(B0, buf, 0);
    if (pf) { stage_half(nbuf, ks + 1, 0, 0); stage_half(nbuf, ks + 1, 0, 1); }
    asm volatile("s_waitcnt lgkmcnt(8)" ::: "memory");  // drain oldest 4 early
    BAR();
    asm volatile("s_waitcnt lgkmcnt(0)" ::: "memory");
    __builtin_amdgcn_sched_barrier(0);
    cluster(A0, B0, 0, 0);
    BAR();

    // ---- ph1: cluster (0,1); reads RB1; stage B-halves of ks+1 ----
    readB(B1, buf, 1);
    if (pf) { stage_half(nbuf, ks + 1, 1, 0); stage_half(nbuf, ks + 1, 1, 1); }
    BAR();
    asm volatile("s_waitcnt lgkmcnt(0)" ::: "memory");
    __builtin_amdgcn_sched_barrier(0);
    cluster(A0, B1, 0, 1);
    BAR();

    // ---- ph2: cluster (1,0); reads RA1 ----
    readA(A1, buf, 1);
    BAR();
    asm volatile("s_waitcnt lgkmcnt(0)" ::: "memory");
    __builtin_amdgcn_sched_barrier(0);
    cluster(A1, B0, 1, 0);
    BAR();

    // ---- ph3: cluster (1,1); vmcnt(0) (stages issued >=2 phases ago) ----
    asm volatile("s_waitcnt vmcnt(0)" ::: "memory");
    BAR();                               // visibility for nbuf (next tile)
    cluster(A1, B1, 1, 1);               // A1,B1 already lgkm'd (ph1/ph2)
    BAR();
  }

  // ---- epilogue: C/D layout col=lane&15, row=(lane>>4)*4+reg (verified) ----
#pragma unroll
  for (int nj = 0; nj < 4; ++nj) {
    const int n = n0 + wc * 64 + nj * 16 + lr;
    if (n >= N) continue;
    const float pn = psq[n];
#pragma unroll
    for (int mi = 0; mi < 8; ++mi) {
      const int mb = m0 + wr * 128 + mi * 16 + lg * 4;
#pragma unroll
      for (int r = 0; r < 4; ++r) {
        const int m = mb + r;
        if (m < M) {
          const float d2 = fsq[m] + pn - 2.f * acc[mi][nj][r];
          out[(size_t)m * N + n] = -sqrtf(fmaxf(d2, 0.f));
        }
      }
    }
  }
}

// ------------------------------------ fallback (round-2 verified, fused) ----
#define BM 128
#define BN 128
#define BKS 32
#define NSTEPS (KDIM / BKS)

__global__ __launch_bounds__(256) void dist_mfma_kernel(
    const void* __restrict__ Araw, const void* __restrict__ Braw,
    float* __restrict__ out, int M, int N) {
  __shared__ uint32_t Ah[2][BM][16];
  __shared__ uint32_t Bh[2][BN][16];
  __shared__ float fsqs[BM];
  __shared__ float psqs[BN];

  const bool isf32 = sniff_is_f32(Araw);
  const int tid = threadIdx.x;
  const int lane = tid & 63;
  const int wave = tid >> 6;
  const int m0 = blockIdx.y * BM;
  const int n0 = blockIdx.x * BN;

  const float* A32 = (const float*)Araw;
  const float* B32 = (const float*)Braw;
  const uint16_t* A16 = (const uint16_t*)Araw;
  const uint16_t* B16 = (const uint16_t*)Braw;

  const int crow = tid >> 2;
  const int cch = tid & 3;
  const int wr = wave >> 1;
  const int wc = wave & 1;
  const int lr = lane & 15;
  const int lg = lane >> 4;

  uint4 qa0[2], qa1[2], qb0[2], qb1[2];
  float na[2] = {0.f, 0.f};
  float nb[2] = {0.f, 0.f};

  auto load_step = [&](int ks) {
#pragma unroll
    for (int s = 0; s < 2; ++s) {
      const int row = crow + 64 * s;
      int gm = m0 + row; gm = gm < M ? gm : M - 1;
      int gn = n0 + row; gn = gn < N ? gn : N - 1;
      const size_t ea = (size_t)gm * KDIM + ks * BKS + cch * 8;
      const size_t eb = (size_t)gn * KDIM + ks * BKS + cch * 8;
      if (isf32) {
        qa0[s] = *(const uint4*)(A32 + ea);
        qa1[s] = *(const uint4*)(A32 + ea + 4);
        qb0[s] = *(const uint4*)(B32 + eb);
        qb1[s] = *(const uint4*)(B32 + eb + 4);
      } else {
        qa0[s] = *(const uint4*)(A16 + ea);
        qb0[s] = *(const uint4*)(B16 + eb);
      }
    }
  };

  auto store_step = [&](int b) {
#pragma unroll
    for (int s = 0; s < 2; ++s) {
      const int row = crow + 64 * s;
      const int pc = (cch ^ ((row >> 1) & 3)) * 4;
      if (isf32) {
        const uint32_t ua[8] = {qa0[s].x, qa0[s].y, qa0[s].z, qa0[s].w,
                                qa1[s].x, qa1[s].y, qa1[s].z, qa1[s].w};
        const uint32_t ub[8] = {qb0[s].x, qb0[s].y, qb0[s].z, qb0[s].w,
                                qb1[s].x, qb1[s].y, qb1[s].z, qb1[s].w};
        float sa = 0.f, sb = 0.f;
#pragma unroll
        for (int j = 0; j < 8; ++j) {
          const float fa = __uint_as_float(ua[j]);
          const float fb = __uint_as_float(ub[j]);
          sa = fmaf(fa, fa, sa);
          sb = fmaf(fb, fb, sb);
        }
        na[s] += sa; nb[s] += sb;
        uint4 pa = {pack_rn(ua[0], ua[1]), pack_rn(ua[2], ua[3]),
                    pack_rn(ua[4], ua[5]), pack_rn(ua[6], ua[7])};
        uint4 pb = {pack_rn(ub[0], ub[1]), pack_rn(ub[2], ub[3]),
                    pack_rn(ub[4], ub[5]), pack_rn(ub[6], ub[7])};
        *(uint4*)&Ah[b][row][pc] = pa;
        *(uint4*)&Bh[b][row][pc] = pb;
      } else {
        float sa = 0.f, sb = 0.f;
        const uint32_t va[4] = {qa0[s].x, qa0[s].y, qa0[s].z, qa0[s].w};
        const uint32_t vb[4] = {qb0[s].x, qb0[s].y, qb0[s].z, qb0[s].w};
#pragma unroll
        for (int j = 0; j < 4; ++j) {
          const float a0 = __uint_as_float(va[j] << 16);
          const float a1 = __uint_as_float(va[j] & 0xFFFF0000u);
          const float b0 = __uint_as_float(vb[j] << 16);
          const float b1 = __uint_as_float(vb[j] & 0xFFFF0000u);
          sa = fmaf(a0, a0, fmaf(a1, a1, sa));
          sb = fmaf(b0, b0, fmaf(b1, b1, sb));
        }
        na[s] += sa; nb[s] += sb;
        *(uint4*)&Ah[b][row][pc] = qa0[s];
        *(uint4*)&Bh[b][row][pc] = qb0[s];
      }
    }
  };

  f32x4 acc[4][4] = {};
  load_step(0);
  store_step(0);
  __syncthreads();

  for (int ks = 0; ks < NSTEPS; ++ks) {
    const int buf = ks & 1;
    const int nxt = ks + 1;
    if (nxt < NSTEPS) load_step(nxt);

    bf16x8 ah[4], bh[4];
#pragma unroll
    for (int i = 0; i < 4; ++i) {
      const int r = wr * 64 + i * 16 + lr;
      const int pc = (lg ^ ((r >> 1) & 3)) * 4;
      ah[i] = *(const bf16x8*)&Ah[buf][r][pc];
    }
#pragma unroll
    for (int j = 0; j < 4; ++j) {
      const int r = wc * 64 + j * 16 + lr;
      const int pc = (lg ^ ((r >> 1) & 3)) * 4;
      bh[j] = *(const bf16x8*)&Bh[buf][r][pc];
    }

#pragma unroll
    for (int i = 0; i < 4; ++i)
#pragma unroll
      for (int j = 0; j < 4; ++j)
        acc[i][j] = __builtin_amdgcn_mfma_f32_16x16x32_bf16(ah[i], bh[j],
                                                            acc[i][j], 0, 0, 0);

    if (nxt < NSTEPS) store_step(nxt & 1);
    __syncthreads();
  }

  float v0 = na[0], v1 = na[1], w0 = nb[0], w1 = nb[1];
#pragma unroll
  for (int o = 1; o <= 2; o <<= 1) {
    v0 += __shfl_xor(v0, o);
    v1 += __shfl_xor(v1, o);
    w0 += __shfl_xor(w0, o);
    w1 += __shfl_xor(w1, o);
  }
  if (cch == 0) {
    fsqs[crow] = v0;
    fsqs[crow + 64] = v1;
    psqs[crow] = w0;
    psqs[crow + 64] = w1;
  }
  __syncthreads();

#pragma unroll
  for (int j = 0; j < 4; ++j) {
    const int nn = wc * 64 + j * 16 + lr;
    const int n = n0 + nn;
    if (n >= N) continue;
    const float pn = psqs[nn];
#pragma unroll
    for (int i = 0; i < 4; ++i) {
      const int mb = wr * 64 + i * 16 + lg * 4;
#pragma unroll
      for (int r = 0; r < 4; ++r) {
        const int m = m0 + mb + r;
        if (m < M) {
          const float d2 = fsqs[mb + r] + pn - 2.f * acc[i][j][r];
          out[(size_t)m * N + n] = -sqrtf(fmaxf(d2, 0.f));
        }
      }
    }
  }
}

// -------------------------------------------------------------- launcher ----
extern "C" void kernel_launch(void* const* d_in, const int* in_sizes, int n_in,
                              void* d_out, int out_size, void* d_ws,
                              size_t ws_size, hipStream_t stream) {
  (void)n_in; (void)out_size;
  const void* feat = d_in[0];
  const void* prot = d_in[1];
  float* out = (float*)d_out;

  const int M = in_sizes[0] / KDIM;  // 16384 (element counts, dtype-free)
  const int N = in_sizes[1] / KDIM;  // 1000

  // ws layout: Abf [M*K bf16] | Bbf [N*K bf16] | fsq [M f32] | psq [N f32]
  const size_t bfA = (size_t)M * KDIM * sizeof(uint16_t);
  const size_t bfB = (size_t)N * KDIM * sizeof(uint16_t);
  const size_t ws_need = bfA + bfB + (size_t)(M + N) * sizeof(float);

  if (d_ws != nullptr && ws_size >= ws_need) {
    uint16_t* Abf = (uint16_t*)d_ws;
    uint16_t* Bbf = (uint16_t*)((char*)d_ws + bfA);
    float* fsq = (float*)((char*)d_ws + bfA + bfB);
    float* psq = fsq + M;
    const int rows = M + N;
    prep_kernel<<<dim3((rows + 3) / 4), dim3(256), 0, stream>>>(
        feat, prot, Abf, Bbf, fsq, psq, M, N);
    dim3 grid((N + BN2 - 1) / BN2, (M + BM2 - 1) / BM2);
    gemm_kernel<<<grid, dim3(512), 0, stream>>>(Abf, Bbf, fsq, psq, out, M, N);
  } else {
    dim3 grid((N + BN - 1) / BN, (M + BM - 1) / BM);
    dist_mfma_kernel<<<grid, dim3(256), 0, stream>>>(feat, prot, out, M, N);
  }
}

// Round 7
// 323.644 us; speedup vs baseline: 1.0168x; 1.0168x over previous
//
#include <hip/hip_runtime.h>
#include <stdint.h>

// out[m,n] = -sqrt( ||A[m]||^2 + ||B[n]||^2 - 2*A[m].B[n] )
// A = features [M=16384, K=2048], B = prototypes [N=1000, K=2048].
//
// Stage plan (ws >= 71.3 MB):
//  1. prep_kernel: fp32 -> bf16(rne) of A,B into workspace + exact fp32 row
//     norms. (bf16 input: plain copy + norms.)
//  2. gemm_kernel: 256x256 tile, BK=64, 512 threads (8 waves, 2Mx4N), 128 KiB
//     double-buffered LDS, 16x16x32 bf16 MFMA. Light-touch 4-phase schedule
//     (m201-faithful): per K-tile, 4 quadrant-clusters of 16 MFMA; each phase
//     = {C++ ds_reads for cluster || stage slice -> ONE s_barrier -> setprio
//     MFMA cluster}. No sched_barrier / no asm lgkmcnt (compiler inserts
//     exact lgkm waits -- round-6's pinning caused 1.2e7 conflict cycles and
//     a regression). vmcnt(0) once per tile at ph3 (stages issued ~2.5
//     phases earlier -> free). Linear LDS dest + inverse-swizzled global
//     source (chunk ^= row&7). Grid 256 blocks = 1/CU; XCD-chunked swizzle.
//  3. ws too small -> round-2 verified fused kernel (correctness fallback).

#define KDIM 2048

typedef __attribute__((ext_vector_type(8))) __bf16 bf16x8;
typedef __attribute__((ext_vector_type(4))) float f32x4;

#define BAR() do { asm volatile("" ::: "memory"); __builtin_amdgcn_s_barrier(); asm volatile("" ::: "memory"); } while (0)

__device__ __forceinline__ bool sniff_is_f32(const void* Araw) {
  // bf16 N(0,1) data -> max |x| < 10; fp32 data -> mantissa half-words give
  // |x| > 1e4 essentially surely. Uniform across all blocks/lanes.
  const uint16_t* sniff = (const uint16_t*)Araw;
  float mx = 0.f;
#pragma unroll
  for (int i = 0; i < 64; ++i) {
    float v = __uint_as_float(((uint32_t)sniff[i]) << 16);
    mx = fmaxf(mx, fabsf(v));
  }
  return mx > 1e4f;
}

__device__ __forceinline__ uint32_t bf16rn(uint32_t u) {
  // fp32 bits -> bf16 bits, round-to-nearest-even (finite inputs only)
  return (u + 0x7FFFu + ((u >> 16) & 1u)) >> 16;
}
__device__ __forceinline__ uint32_t pack_rn(uint32_t a, uint32_t b) {
  return bf16rn(a) | (bf16rn(b) << 16);
}

__device__ __forceinline__ void gload_lds16(const void* g, void* l) {
  // async 16B global -> LDS; dest = wave-uniform base + lane*16
  __builtin_amdgcn_global_load_lds(
      (const __attribute__((address_space(1))) void*)g,
      (__attribute__((address_space(3))) void*)l, 16, 0, 0);
}

// ----------------------------------------------------- prepass: cvt+norms ----
// one wave per row; 4 rows per 256-thread block
__global__ __launch_bounds__(256) void prep_kernel(
    const void* __restrict__ Araw, const void* __restrict__ Braw,
    uint16_t* __restrict__ Abf, uint16_t* __restrict__ Bbf,
    float* __restrict__ fsq, float* __restrict__ psq, int M, int N) {
  const bool isf32 = sniff_is_f32(Araw);
  const int wave = threadIdx.x >> 6;
  const int lane = threadIdx.x & 63;
  const int row = blockIdx.x * 4 + wave;
  if (row >= M + N) return;
  const bool isA = row < M;
  const size_t r = isA ? (size_t)row : (size_t)(row - M);
  uint2* dst = (uint2*)((isA ? Abf : Bbf) + r * KDIM);
  float s = 0.f;
  if (isf32) {
    const float* p = (isA ? (const float*)Araw : (const float*)Braw) + r * KDIM;
#pragma unroll
    for (int it = 0; it < KDIM / 256; ++it) {
      float4 v = *((const float4*)p + it * 64 + lane);
      s = fmaf(v.x, v.x, fmaf(v.y, v.y, fmaf(v.z, v.z, fmaf(v.w, v.w, s))));
      uint2 o;
      o.x = pack_rn(__float_as_uint(v.x), __float_as_uint(v.y));
      o.y = pack_rn(__float_as_uint(v.z), __float_as_uint(v.w));
      dst[it * 64 + lane] = o;
    }
  } else {
    const uint16_t* p =
        (isA ? (const uint16_t*)Araw : (const uint16_t*)Braw) + r * KDIM;
#pragma unroll
    for (int it = 0; it < KDIM / 256; ++it) {
      uint2 v = *((const uint2*)p + it * 64 + lane);
      float e0 = __uint_as_float(v.x << 16);
      float e1 = __uint_as_float(v.x & 0xFFFF0000u);
      float e2 = __uint_as_float(v.y << 16);
      float e3 = __uint_as_float(v.y & 0xFFFF0000u);
      s = fmaf(e0, e0, fmaf(e1, e1, fmaf(e2, e2, fmaf(e3, e3, s))));
      dst[it * 64 + lane] = v;
    }
  }
#pragma unroll
  for (int o = 32; o > 0; o >>= 1) s += __shfl_down(s, o, 64);
  if (lane == 0) {
    if (isA) fsq[r] = s;
    else     psq[r] = s;
  }
}

// --------------------------------------------------- GEMM 256x256, BK=64 ----
#define BM2 256
#define BN2 256
#define BK2 64
#define NK2 (KDIM / BK2)   // 32

__global__ __launch_bounds__(512, 2) void gemm_kernel(
    const uint16_t* __restrict__ Abf, const uint16_t* __restrict__ Bbf,
    const float* __restrict__ fsq, const float* __restrict__ psq,
    float* __restrict__ out, int M, int N) {
  // row = 64 bf16 = 128 B = 8 chunks of 16 B. LDS chunk c of row r holds
  // global k-chunk c ^ (r&7)  (inverse-swizzled SOURCE, linear dest).
  __shared__ uint32_t Ab[2][BM2][32];  // 64 KB
  __shared__ uint32_t Bb[2][BN2][32];  // 64 KB

  const int tid = threadIdx.x;
  const int lane = tid & 63;
  const int wave = tid >> 6;   // 0..7

  // XCD-chunked block swizzle (nwg = 256, divisible by 8 -> bijective).
  const int gx = gridDim.x, gy = gridDim.y;
  const int nwg = gx * gy;
  int id = blockIdx.y * gx + blockIdx.x;
  if ((nwg & 7) == 0) id = (id & 7) * (nwg >> 3) + (id >> 3);
  const int m0 = (id / gx) * BM2;
  const int n0 = (id % gx) * BN2;

  const int wr = wave >> 2;   // 0..1: 128-row band
  const int wc = wave & 3;    // 0..3: 64-col band
  const int lr = lane & 15;   // fragment row/col within 16
  const int lg = lane >> 4;   // k-group within 4

  const int wbase = (tid & ~63);  // wave*64, uniform in wave

  // stage one half-tile (128 rows) of matrix mat into buffer b for K-tile ks
  auto stage_half = [&](int b, int ks, int mat, int h) {
#pragma unroll
    for (int l = 0; l < 2; ++l) {
      const int f = l * 512 + tid;          // 16B-chunk id within half
      const int row = h * 128 + (f >> 3);
      const int gc = (f & 7) ^ (row & 7);   // pre-swizzled source chunk
      uint32_t* base = mat ? &Bb[b][0][0] : &Ab[b][0][0];
      uint32_t* dst = base + h * 4096 + (l * 512 + wbase) * 4;  // wave-uniform
      const int lim = mat ? N : M;
      int g = (mat ? n0 : m0) + row;
      g = g < lim ? g : lim - 1;            // clamp tail rows
      const uint16_t* G = mat ? Bbf : Abf;
      gload_lds16(G + (size_t)g * KDIM + ks * BK2 + gc * 8, dst);
    }
  };

  bf16x8 A0[4][2], A1[4][2], B0[2][2], B1[2][2];

  auto readA = [&](bf16x8 (&dst)[4][2], int b, int mh) {
#pragma unroll
    for (int i = 0; i < 4; ++i) {
      const int r = wr * 128 + (mh * 4 + i) * 16 + lr;
#pragma unroll
      for (int kk = 0; kk < 2; ++kk) {
        const int pc = (((kk << 2) + lg) ^ (r & 7)) * 4;
        dst[i][kk] = *(const bf16x8*)&Ab[b][r][pc];
      }
    }
  };
  auto readB = [&](bf16x8 (&dst)[2][2], int b, int nh) {
#pragma unroll
    for (int j = 0; j < 2; ++j) {
      const int r = wc * 64 + (nh * 2 + j) * 16 + lr;
#pragma unroll
      for (int kk = 0; kk < 2; ++kk) {
        const int pc = (((kk << 2) + lg) ^ (r & 7)) * 4;
        dst[j][kk] = *(const bf16x8*)&Bb[b][r][pc];
      }
    }
  };

  f32x4 acc[8][4] = {};

  auto cluster = [&](bf16x8 (&A)[4][2], bf16x8 (&B)[2][2], int mh, int nh) {
    __builtin_amdgcn_s_setprio(1);
#pragma unroll
    for (int i = 0; i < 4; ++i)
#pragma unroll
      for (int j = 0; j < 2; ++j)
#pragma unroll
        for (int kk = 0; kk < 2; ++kk)
          acc[mh * 4 + i][nh * 2 + j] = __builtin_amdgcn_mfma_f32_16x16x32_bf16(
              A[i][kk], B[j][kk], acc[mh * 4 + i][nh * 2 + j], 0, 0, 0);
    __builtin_amdgcn_s_setprio(0);
  };

  // prologue: stage K-tile 0 fully, drain, visibility barrier
  stage_half(0, 0, 0, 0); stage_half(0, 0, 0, 1);
  stage_half(0, 0, 1, 0); stage_half(0, 0, 1, 1);
  asm volatile("s_waitcnt vmcnt(0)" ::: "memory");
  BAR();

  for (int ks = 0; ks < NK2; ++ks) {
    const int buf = ks & 1, nbuf = buf ^ 1;
    const bool pf = (ks + 1 < NK2);

    // ph0: reads for cluster(0,0) + stage A-halves of ks+1 -> BAR -> MFMA.
    // Compiler inserts the exact lgkm waits before first MFMA use (no
    // pinning -- round-6's asm-lgkm + sched_barrier caused the regression).
    readA(A0, buf, 0);
    readB(B0, buf, 0);
    if (pf) { stage_half(nbuf, ks + 1, 0, 0); stage_half(nbuf, ks + 1, 0, 1); }
    BAR();
    cluster(A0, B0, 0, 0);

    // ph1: reads B1 + stage B-halves of ks+1 -> BAR -> MFMA (0,1)
    readB(B1, buf, 1);
    if (pf) { stage_half(nbuf, ks + 1, 1, 0); stage_half(nbuf, ks + 1, 1, 1); }
    BAR();
    cluster(A0, B1, 0, 1);

    // ph2: reads A1 -> BAR -> MFMA (1,0)
    readA(A1, buf, 1);
    BAR();
    cluster(A1, B0, 1, 0);

    // ph3: vmcnt(0) (ks+1 stages issued ~2.5 phases ago -> ~free) -> BAR
    // (nbuf visibility for next tile's ph0) -> MFMA (1,1) on registers.
    asm volatile("s_waitcnt vmcnt(0)" ::: "memory");
    BAR();
    cluster(A1, B1, 1, 1);
  }

  // ---- epilogue: C/D layout col=lane&15, row=(lane>>4)*4+reg (verified) ----
#pragma unroll
  for (int nj = 0; nj < 4; ++nj) {
    const int n = n0 + wc * 64 + nj * 16 + lr;
    if (n >= N) continue;
    const float pn = psq[n];
#pragma unroll
    for (int mi = 0; mi < 8; ++mi) {
      const int mb = m0 + wr * 128 + mi * 16 + lg * 4;
#pragma unroll
      for (int r = 0; r < 4; ++r) {
        const int m = mb + r;
        if (m < M) {
          const float d2 = fsq[m] + pn - 2.f * acc[mi][nj][r];
          out[(size_t)m * N + n] = -sqrtf(fmaxf(d2, 0.f));
        }
      }
    }
  }
}

// ------------------------------------ fallback (round-2 verified, fused) ----
#define BM 128
#define BN 128
#define BKS 32
#define NSTEPS (KDIM / BKS)

__global__ __launch_bounds__(256) void dist_mfma_kernel(
    const void* __restrict__ Araw, const void* __restrict__ Braw,
    float* __restrict__ out, int M, int N) {
  __shared__ uint32_t Ah[2][BM][16];
  __shared__ uint32_t Bh[2][BN][16];
  __shared__ float fsqs[BM];
  __shared__ float psqs[BN];

  const bool isf32 = sniff_is_f32(Araw);
  const int tid = threadIdx.x;
  const int lane = tid & 63;
  const int wave = tid >> 6;
  const int m0 = blockIdx.y * BM;
  const int n0 = blockIdx.x * BN;

  const float* A32 = (const float*)Araw;
  const float* B32 = (const float*)Braw;
  const uint16_t* A16 = (const uint16_t*)Araw;
  const uint16_t* B16 = (const uint16_t*)Braw;

  const int crow = tid >> 2;
  const int cch = tid & 3;
  const int wr = wave >> 1;
  const int wc = wave & 1;
  const int lr = lane & 15;
  const int lg = lane >> 4;

  uint4 qa0[2], qa1[2], qb0[2], qb1[2];
  float na[2] = {0.f, 0.f};
  float nb[2] = {0.f, 0.f};

  auto load_step = [&](int ks) {
#pragma unroll
    for (int s = 0; s < 2; ++s) {
      const int row = crow + 64 * s;
      int gm = m0 + row; gm = gm < M ? gm : M - 1;
      int gn = n0 + row; gn = gn < N ? gn : N - 1;
      const size_t ea = (size_t)gm * KDIM + ks * BKS + cch * 8;
      const size_t eb = (size_t)gn * KDIM + ks * BKS + cch * 8;
      if (isf32) {
        qa0[s] = *(const uint4*)(A32 + ea);
        qa1[s] = *(const uint4*)(A32 + ea + 4);
        qb0[s] = *(const uint4*)(B32 + eb);
        qb1[s] = *(const uint4*)(B32 + eb + 4);
      } else {
        qa0[s] = *(const uint4*)(A16 + ea);
        qb0[s] = *(const uint4*)(B16 + eb);
      }
    }
  };

  auto store_step = [&](int b) {
#pragma unroll
    for (int s = 0; s < 2; ++s) {
      const int row = crow + 64 * s;
      const int pc = (cch ^ ((row >> 1) & 3)) * 4;
      if (isf32) {
        const uint32_t ua[8] = {qa0[s].x, qa0[s].y, qa0[s].z, qa0[s].w,
                                qa1[s].x, qa1[s].y, qa1[s].z, qa1[s].w};
        const uint32_t ub[8] = {qb0[s].x, qb0[s].y, qb0[s].z, qb0[s].w,
                                qb1[s].x, qb1[s].y, qb1[s].z, qb1[s].w};
        float sa = 0.f, sb = 0.f;
#pragma unroll
        for (int j = 0; j < 8; ++j) {
          const float fa = __uint_as_float(ua[j]);
          const float fb = __uint_as_float(ub[j]);
          sa = fmaf(fa, fa, sa);
          sb = fmaf(fb, fb, sb);
        }
        na[s] += sa; nb[s] += sb;
        uint4 pa = {pack_rn(ua[0], ua[1]), pack_rn(ua[2], ua[3]),
                    pack_rn(ua[4], ua[5]), pack_rn(ua[6], ua[7])};
        uint4 pb = {pack_rn(ub[0], ub[1]), pack_rn(ub[2], ub[3]),
                    pack_rn(ub[4], ub[5]), pack_rn(ub[6], ub[7])};
        *(uint4*)&Ah[b][row][pc] = pa;
        *(uint4*)&Bh[b][row][pc] = pb;
      } else {
        float sa = 0.f, sb = 0.f;
        const uint32_t va[4] = {qa0[s].x, qa0[s].y, qa0[s].z, qa0[s].w};
        const uint32_t vb[4] = {qb0[s].x, qb0[s].y, qb0[s].z, qb0[s].w};
#pragma unroll
        for (int j = 0; j < 4; ++j) {
          const float a0 = __uint_as_float(va[j] << 16);
          const float a1 = __uint_as_float(va[j] & 0xFFFF0000u);
          const float b0 = __uint_as_float(vb[j] << 16);
          const float b1 = __uint_as_float(vb[j] & 0xFFFF0000u);
          sa = fmaf(a0, a0, fmaf(a1, a1, sa));
          sb = fmaf(b0, b0, fmaf(b1, b1, sb));
        }
        na[s] += sa; nb[s] += sb;
        *(uint4*)&Ah[b][row][pc] = qa0[s];
        *(uint4*)&Bh[b][row][pc] = qb0[s];
      }
    }
  };

  f32x4 acc[4][4] = {};
  load_step(0);
  store_step(0);
  __syncthreads();

  for (int ks = 0; ks < NSTEPS; ++ks) {
    const int buf = ks & 1;
    const int nxt = ks + 1;
    if (nxt < NSTEPS) load_step(nxt);

    bf16x8 ah[4], bh[4];
#pragma unroll
    for (int i = 0; i < 4; ++i) {
      const int r = wr * 64 + i * 16 + lr;
      const int pc = (lg ^ ((r >> 1) & 3)) * 4;
      ah[i] = *(const bf16x8*)&Ah[buf][r][pc];
    }
#pragma unroll
    for (int j = 0; j < 4; ++j) {
      const int r = wc * 64 + j * 16 + lr;
      const int pc = (lg ^ ((r >> 1) & 3)) * 4;
      bh[j] = *(const bf16x8*)&Bh[buf][r][pc];
    }

#pragma unroll
    for (int i = 0; i < 4; ++i)
#pragma unroll
      for (int j = 0; j < 4; ++j)
        acc[i][j] = __builtin_amdgcn_mfma_f32_16x16x32_bf16(ah[i], bh[j],
                                                            acc[i][j], 0, 0, 0);

    if (nxt < NSTEPS) store_step(nxt & 1);
    __syncthreads();
  }

  float v0 = na[0], v1 = na[1], w0 = nb[0], w1 = nb[1];
#pragma unroll
  for (int o = 1; o <= 2; o <<= 1) {
    v0 += __shfl_xor(v0, o);
    v1 += __shfl_xor(v1, o);
    w0 += __shfl_xor(w0, o);
    w1 += __shfl_xor(w1, o);
  }
  if (cch == 0) {
    fsqs[crow] = v0;
    fsqs[crow + 64] = v1;
    psqs[crow] = w0;
    psqs[crow + 64] = w1;
  }
  __syncthreads();

#pragma unroll
  for (int j = 0; j < 4; ++j) {
    const int nn = wc * 64 + j * 16 + lr;
    const int n = n0 + nn;
    if (n >= N) continue;
    const float pn = psqs[nn];
#pragma unroll
    for (int i = 0; i < 4; ++i) {
      const int mb = wr * 64 + i * 16 + lg * 4;
#pragma unroll
      for (int r = 0; r < 4; ++r) {
        const int m = m0 + mb + r;
        if (m < M) {
          const float d2 = fsqs[mb + r] + pn - 2.f * acc[i][j][r];
          out[(size_t)m * N + n] = -sqrtf(fmaxf(d2, 0.f));
        }
      }
    }
  }
}

// -------------------------------------------------------------- launcher ----
extern "C" void kernel_launch(void* const* d_in, const int* in_sizes, int n_in,
                              void* d_out, int out_size, void* d_ws,
                              size_t ws_size, hipStream_t stream) {
  (void)n_in; (void)out_size;
  const void* feat = d_in[0];
  const void* prot = d_in[1];
  float* out = (float*)d_out;

  const int M = in_sizes[0] / KDIM;  // 16384 (element counts, dtype-free)
  const int N = in_sizes[1] / KDIM;  // 1000

  // ws layout: Abf [M*K bf16] | Bbf [N*K bf16] | fsq [M f32] | psq [N f32]
  const size_t bfA = (size_t)M * KDIM * sizeof(uint16_t);
  const size_t bfB = (size_t)N * KDIM * sizeof(uint16_t);
  const size_t ws_need = bfA + bfB + (size_t)(M + N) * sizeof(float);

  if (d_ws != nullptr && ws_size >= ws_need) {
    uint16_t* Abf = (uint16_t*)d_ws;
    uint16_t* Bbf = (uint16_t*)((char*)d_ws + bfA);
    float* fsq = (float*)((char*)d_ws + bfA + bfB);
    float* psq = fsq + M;
    const int rows = M + N;
    prep_kernel<<<dim3((rows + 3) / 4), dim3(256), 0, stream>>>(
        feat, prot, Abf, Bbf, fsq, psq, M, N);
    dim3 grid((N + BN2 - 1) / BN2, (M + BM2 - 1) / BM2);
    gemm_kernel<<<grid, dim3(512), 0, stream>>>(Abf, Bbf, fsq, psq, out, M, N);
  } else {
    dim3 grid((N + BN - 1) / BN, (M + BM - 1) / BM);
    dist_mfma_kernel<<<grid, dim3(256), 0, stream>>>(feat, prot, out, M, N);
  }
}